// Round 5
// baseline (183.439 us; speedup 1.0000x reference)
//
#include <hip/hip_runtime.h>
#include <math.h>

// Problem constants (B=64, J=17, H=W=128)
#define BJ    1088               // B*J maps per tensor
#define NMAP  (2 * BJ)           // 2176 total maps (pred then gt)
#define HW    16384              // 128*128
#define NTH   256                // copy-µbench-like block size
#define CPM   4                  // chunks per map (4096 elems per chunk)
#define NCHK  (NMAP * CPM)       // 8704 blocks per streaming pass
#define F4PT  4                  // float4 per thread (16 elems)

// ws layout: keys ull[NMAP] | sums f32[NMAP] | cnts f32[NMAP]
#define SUMS_OFF (NMAP)                  // in u64 units for key array end
// Monotonic unsigned key for float bits: orders like float compare.
__device__ __forceinline__ unsigned int ford(unsigned int u) {
    return (u & 0x80000000u) ? ~u : (u | 0x80000000u);
}
__device__ __forceinline__ unsigned int ford_inv(unsigned int o) {
    return (o & 0x80000000u) ? (o & 0x7fffffffu) : ~o;
}

__device__ __forceinline__ const float* map_ptr(const float* outp, const float* tgtp, int m) {
    return (m < BJ) ? (outp + (size_t)m * HW) : (tgtp + (size_t)(m - BJ) * HW);
}

// Zero the 34816-byte accumulator region (keys + sums + cnts).
__global__ __launch_bounds__(512) void ws_init(unsigned int* __restrict__ w) {
    const int n = NMAP * 2 + NMAP + NMAP;          // u32 words: keys(2/map)+sum+cnt
    for (int i = threadIdx.x; i < n; i += 512) w[i] = 0u;
}

// Pass A: pure streaming read, copy-identical pattern. Each block owns one
// contiguous 16 KB chunk of one map; block-reduce (max, first-idx) as a
// packed u64 key; one device atomicMax per chunk. ford(v)>0 for all reals,
// so zero-init is the identity.
__global__ __launch_bounds__(NTH) void map_max(const float* __restrict__ outp,
                                               const float* __restrict__ tgtp,
                                               unsigned long long* __restrict__ keys)
{
    __shared__ unsigned long long rk[NTH / 64];
    const int gid   = blockIdx.x;        // [0, NCHK)
    const int m     = gid >> 2;
    const int chunk = gid & 3;
    const float4* __restrict__ s4 = (const float4*)map_ptr(outp, tgtp, m) + chunk * 1024;
    const int t = threadIdx.x;

    float lmax = -INFINITY;
    int   lidx = 0;
#pragma unroll
    for (int k = 0; k < F4PT; ++k) {     // element idx grows with k -> '>' keeps first
        const float4 v = s4[t + k * NTH];
        const int base = (chunk * 1024 + t + k * NTH) << 2;
        if (v.x > lmax) { lmax = v.x; lidx = base;     }
        if (v.y > lmax) { lmax = v.y; lidx = base + 1; }
        if (v.z > lmax) { lmax = v.z; lidx = base + 2; }
        if (v.w > lmax) { lmax = v.w; lidx = base + 3; }
    }
    // (ord(value)<<32) | ~idx : u64 max == (max value, then min idx)
    unsigned long long key =
        ((unsigned long long)ford(__float_as_uint(lmax)) << 32) | (unsigned int)~lidx;
#pragma unroll
    for (int off = 32; off >= 1; off >>= 1) {
        const unsigned long long ok = __shfl_down(key, off, 64);
        key = (ok > key) ? ok : key;
    }
    const int wave = t >> 6, lane = t & 63;
    if (lane == 0) rk[wave] = key;
    __syncthreads();
    if (t == 0) {
#pragma unroll
        for (int w = 1; w < NTH / 64; ++w) key = (rk[w] > key) ? rk[w] : key;
        atomicMax(&keys[m], key);
    }
}

// Pass B: second stream (L3-resident), masked distance sums, one atomicAdd
// pair per chunk.
__global__ __launch_bounds__(NTH) void map_sum(const float* __restrict__ outp,
                                               const float* __restrict__ tgtp,
                                               const unsigned long long* __restrict__ keys,
                                               float* __restrict__ sums,
                                               float* __restrict__ cnts)
{
    __shared__ float rs[NTH / 64], rc[NTH / 64];
    const int gid   = blockIdx.x;
    const int m     = gid >> 2;
    const int chunk = gid & 3;
    const float4* __restrict__ s4 = (const float4*)map_ptr(outp, tgtp, m) + chunk * 1024;
    const int t = threadIdx.x;

    const unsigned long long bk = keys[m];
    const float maxv = __uint_as_float(ford_inv((unsigned int)(bk >> 32)));
    const int   midx = (int)~(unsigned int)(bk & 0xffffffffu);
    const float ym  = (float)(midx >> 7);     // reference: idx // H (H=128 stride)
    const float xm  = (float)(midx & 127);
    const float thv = maxv * 0.5f;

    float s = 0.0f, c = 0.0f;
#pragma unroll
    for (int k = 0; k < F4PT; ++k) {
        const float4 v = s4[t + k * NTH];
        const int g4  = chunk * 1024 + t + k * NTH;
        const float dy  = (float)(g4 >> 5) - ym;          // all 4 elems share a row
        const float dy2 = dy * dy;
        const float cb  = (float)((g4 << 2) & 127) - xm;
        {
            const float dx = cb;        const float d0 = __builtin_amdgcn_sqrtf(fmaf(dx, dx, dy2));
            const float mk = (v.x > thv) ? 1.0f : 0.0f;  s = fmaf(mk, d0, s);  c += mk;
        }
        {
            const float dx = cb + 1.0f; const float d0 = __builtin_amdgcn_sqrtf(fmaf(dx, dx, dy2));
            const float mk = (v.y > thv) ? 1.0f : 0.0f;  s = fmaf(mk, d0, s);  c += mk;
        }
        {
            const float dx = cb + 2.0f; const float d0 = __builtin_amdgcn_sqrtf(fmaf(dx, dx, dy2));
            const float mk = (v.z > thv) ? 1.0f : 0.0f;  s = fmaf(mk, d0, s);  c += mk;
        }
        {
            const float dx = cb + 3.0f; const float d0 = __builtin_amdgcn_sqrtf(fmaf(dx, dx, dy2));
            const float mk = (v.w > thv) ? 1.0f : 0.0f;  s = fmaf(mk, d0, s);  c += mk;
        }
    }
#pragma unroll
    for (int off = 32; off >= 1; off >>= 1) {
        s += __shfl_down(s, off, 64);
        c += __shfl_down(c, off, 64);
    }
    const int wave = t >> 6, lane = t & 63;
    if (lane == 0) { rs[wave] = s; rc[wave] = c; }
    __syncthreads();
    if (t == 0) {
#pragma unroll
        for (int w = 1; w < NTH / 64; ++w) { s += rs[w]; c += rc[w]; }
        atomicAdd(&sums[m], s);
        atomicAdd(&cnts[m], c);
    }
}

// Pass C: finalize 1088 pairs -> scalar loss.
__global__ __launch_bounds__(256) void finalize(const unsigned long long* __restrict__ keys,
                                                const float* __restrict__ sums,
                                                const float* __restrict__ cnts,
                                                float* __restrict__ out)
{
    __shared__ float rs[4];
    const int t = threadIdx.x;
    float acc = 0.0f;
    for (int i = t; i < BJ; i += 256) {
        float d2[2];
#pragma unroll
        for (int g = 0; g < 2; ++g) {
            const int m = i + g * BJ;
            const float maxv = __uint_as_float(ford_inv((unsigned int)(keys[m] >> 32)));
            const float s = sums[m], c = cnts[m];
            const float mean = s / fmaxf(c, 1.0f);
            const float dd   = (c > 0.0f) ? (mean / 181.02f) : 1.0f;   // MAX_DIST
            d2[g] = (maxv > 0.0f) ? dd : 0.0f;
        }
        acc += fabsf(d2[1] - d2[0]);
    }
#pragma unroll
    for (int off = 32; off >= 1; off >>= 1) acc += __shfl_down(acc, off, 64);
    const int wave = t >> 6, lane = t & 63;
    if (lane == 0) rs[wave] = acc;
    __syncthreads();
    if (t == 0) {
        acc = rs[0] + rs[1] + rs[2] + rs[3];
        out[0] = acc / 17.0f / 64.0f;      // / J / B, reference order
    }
}

extern "C" void kernel_launch(void* const* d_in, const int* in_sizes, int n_in,
                              void* d_out, int out_size, void* d_ws, size_t ws_size,
                              hipStream_t stream) {
    const float* outp = (const float*)d_in[0];   // [64,17,128,128] f32
    const float* tgtp = (const float*)d_in[1];
    unsigned long long* keys = (unsigned long long*)d_ws;
    float* sums = (float*)((char*)d_ws + NMAP * 8);
    float* cnts = (float*)((char*)d_ws + NMAP * 8 + NMAP * 4);

    ws_init <<<dim3(1),    dim3(512), 0, stream>>>((unsigned int*)d_ws);
    map_max <<<dim3(NCHK), dim3(NTH), 0, stream>>>(outp, tgtp, keys);
    map_sum <<<dim3(NCHK), dim3(NTH), 0, stream>>>(outp, tgtp, keys, sums, cnts);
    finalize<<<dim3(1),    dim3(256), 0, stream>>>(keys, sums, cnts, (float*)d_out);
}